// Round 1
// baseline (3159.445 us; speedup 1.0000x reference)
//
#include <hip/hip_runtime.h>

typedef short bf16x8 __attribute__((ext_vector_type(8)));
typedef float f32x4 __attribute__((ext_vector_type(4)));

#define DEV __device__ __forceinline__

DEV short f2bf(float f) {
  union { float f; unsigned u; } v; v.f = f;
  unsigned r = v.u + 0x7FFFu + ((v.u >> 16) & 1u);
  return (short)(r >> 16);
}
DEV float bf2f(short s) {
  union { unsigned u; float f; } v; v.u = ((unsigned)(unsigned short)s) << 16;
  return v.f;
}
DEV float sigm(float x) { return 1.0f / (1.0f + __expf(-x)); }
DEV float tanh_(float x) {
  float a = fabsf(x);
  float e = __expf(-2.0f * a);
  float t = (1.0f - e) / (1.0f + e);
  return copysignf(t, x);
}

// ---------------- LDS layout (main kernel), byte offsets ----------------
// All bf16 2D arrays use XOR swizzle: byte_in_row ^= (row&7)<<4  (T2/G4)
#define LDS_S   0        // s  : 64 x 128 bf16, stride 256 B
#define LDS_H0  16384    // h0 : 64 x 256 bf16, stride 512 B
#define LDS_H1  49152    // h1 : 64 x 256 bf16, stride 512 B
#define LDS_T   81920    // t  : 64 x 256 bf16, stride 512 B
#define LDS_CF  16384    // cf staging: 64 x 512 bf16, stride 1024 B (overlaps H0+H1)
#define LDS_SZ  114688

// ---------------- workspace offsets (bf16/short elements) ----------------
#define OFF_SE1 0        // N=256 K=512
#define OFF_SE2 131072   // N=128 K=256
#define OFF_W0  163840   // N=1024 K=384 (= [w_ih0 | w_hh0])
#define OFF_W1  557056   // N=1024 K=512 (= [w_ih1 | w_hh1])
#define OFF_OM1 1081344  // N=256 K=384
#define OFF_OM2 1179648  // N=512 K=256
#define OFF_PE1 1310720  // N=128 K=512

// Weight prep: gather into MFMA fragment order.
// element e = ((ntile*KK + kk)*64 + lane)*8 + j  <->  W[ntile*16 + (lane&15)][kk*32 + (lane>>4)*8 + j]
__global__ void prep_frag(const float* __restrict__ srcA, const float* __restrict__ srcB,
                          short* __restrict__ dst, int N, int K, int ksplit)
{
  const int e = blockIdx.x * 256 + threadIdx.x;
  if (e >= N * K) return;
  const int f = e >> 9;
  const int rix = e & 511;
  const int lane = rix >> 3, j = rix & 7;
  const int KK = K >> 5;
  const int ntile = f / KK, kk = f - ntile * KK;
  const int n = ntile * 16 + (lane & 15);
  const int k = kk * 32 + ((lane >> 4) << 3) + j;
  float v;
  if (k < ksplit) v = srcA[(size_t)n * ksplit + k];
  else            v = srcB[(size_t)n * (K - ksplit) + (k - ksplit)];
  dst[e] = f2bf(v);
}

template<int NT, int MT>
DEV void zacc(f32x4 (&acc)[NT][MT]) {
  #pragma unroll
  for (int n = 0; n < NT; ++n)
    #pragma unroll
    for (int m = 0; m < MT; ++m)
      acc[n][m] = (f32x4){0.f, 0.f, 0.f, 0.f};
}

// Generic tile-matmul: acc[nt][m] += A[m-tile] * W[ntBase + nt*ntStride]^T
// A is read from (possibly concatenated) swizzled LDS regions; W from frag-ordered global.
template<int KK, int NT, int MT>
DEV void mm_tiles(const char* sm, int aBase0, int aStride0, int splitKB,
                  int aBase1, int aStride1,
                  const short* __restrict__ wf, int ntBase, int ntStride,
                  f32x4 (&acc)[NT][MT], int lane)
{
  const int l15 = lane & 15, l4 = lane >> 4;
  #pragma unroll
  for (int kk = 0; kk < KK; ++kk) {
    const int kb = kk * 64 + l4 * 16;   // byte offset of this lane's 8 bf16 in the K dim
    bf16x8 a[MT];
    #pragma unroll
    for (int m = 0; m < MT; ++m) {
      const int r = m * 16 + l15;
      int off;
      if (kb < splitKB) off = aBase0 + r * aStride0 + (kb ^ ((r & 7) << 4));
      else              off = aBase1 + r * aStride1 + ((kb - splitKB) ^ ((r & 7) << 4));
      a[m] = *(const bf16x8*)(sm + off);
    }
    #pragma unroll
    for (int nt = 0; nt < NT; ++nt) {
      const bf16x8 b = *(const bf16x8*)(wf + (size_t)((ntBase + nt * ntStride) * KK + kk) * 512 + lane * 8);
      #pragma unroll
      for (int m = 0; m < MT; ++m)
        acc[nt][m] = __builtin_amdgcn_mfma_f32_16x16x32_bf16(a[m], b, acc[nt][m], 0, 0, 0);
    }
  }
}

// LSTM elementwise on a 4-gate accumulator set (gate-local lanes).
DEV void lstm_ew(f32x4 (&acc)[4][4], f32x4 bv, float (&cp)[16], unsigned (&hp)[16], int hoff)
{
  #pragma unroll
  for (int m = 0; m < 4; ++m)
    #pragma unroll
    for (int q = 0; q < 4; ++q) {
      const float gi = acc[0][m][q] + bv[0];
      const float gf = acc[1][m][q] + bv[1];
      const float gg = acc[2][m][q] + bv[2];
      const float go = acc[3][m][q] + bv[3];
      const float c = sigm(gf) * cp[m * 4 + q] + sigm(gi) * tanh_(gg);
      cp[m * 4 + q] = c;
      const float h = sigm(go) * tanh_(c);
      const unsigned hb = (unsigned)(unsigned short)f2bf(h);
      const int pi = hoff + m * 2 + (q >> 1);
      if ((q & 1) == 0) hp[pi] = hb; else hp[pi] |= (hb << 16);
    }
}

// ---------------- main fused kernel: 64 batch rows per workgroup ----------------
__global__ __launch_bounds__(512, 2) void atg_main(
    const float* __restrict__ base, const float* __restrict__ cf,
    const float* __restrict__ b_se1, const float* __restrict__ b_se2,
    const float* __restrict__ b_ih0, const float* __restrict__ b_hh0,
    const float* __restrict__ b_ih1, const float* __restrict__ b_hh1,
    const float* __restrict__ b_om1, const float* __restrict__ b_om2,
    const short* __restrict__ wsb,
    float* __restrict__ outStates, float* __restrict__ outS,
    float* __restrict__ outFinal, int nsteps)
{
  __shared__ __align__(16) char sm[LDS_SZ];
  const int tid = threadIdx.x;
  const int lane = tid & 63, wid = tid >> 6;
  const int l15 = lane & 15, l4 = lane >> 4;
  const int row0 = blockIdx.x * 64;

  // ---- stage counterfactual_scenario -> LDS_CF (bf16, swizzled)
  {
    const int r = tid >> 3, ci = tid & 7;
    const float* src = cf + (size_t)(row0 + r) * 512;
    #pragma unroll
    for (int i = 0; i < 16; ++i) {
      const int c = ci * 4 + i * 32;
      const float4 v = *(const float4*)(src + c);
      short4 h; h.x = f2bf(v.x); h.y = f2bf(v.y); h.z = f2bf(v.z); h.w = f2bf(v.w);
      *(short4*)(sm + LDS_CF + r * 1024 + ((c * 2) ^ ((r & 7) << 4))) = h;
    }
  }
  __syncthreads();

  // ---- se1: relu(cf @ Wse1^T + b_se1) -> tS
  {
    f32x4 acc[2][4]; zacc(acc);
    mm_tiles<16, 2, 4>(sm, LDS_CF, 1024, 1024, LDS_CF, 1024, wsb + OFF_SE1, wid * 2, 1, acc, lane);
    #pragma unroll
    for (int nt = 0; nt < 2; ++nt) {
      const int cc = wid * 32 + nt * 16 + l15;
      const float bv = b_se1[cc];
      #pragma unroll
      for (int m = 0; m < 4; ++m)
        #pragma unroll
        for (int q = 0; q < 4; ++q) {
          const int rr = m * 16 + l4 * 4 + q;
          const float u = fmaxf(acc[nt][m][q] + bv, 0.0f);
          *(short*)(sm + LDS_T + rr * 512 + ((cc * 2) ^ ((rr & 7) << 4))) = f2bf(u);
        }
    }
  }
  __syncthreads();

  // ---- se2: t @ Wse2^T + b_se2 -> sS (bf16) and outS (f32); zero h0/h1
  {
    f32x4 acc[1][4]; zacc(acc);
    mm_tiles<8, 1, 4>(sm, LDS_T, 512, 512, LDS_T, 512, wsb + OFF_SE2, wid, 1, acc, lane);
    const int cc = wid * 16 + l15;
    const float bv = b_se2[cc];
    #pragma unroll
    for (int m = 0; m < 4; ++m)
      #pragma unroll
      for (int q = 0; q < 4; ++q) {
        const int rr = m * 16 + l4 * 4 + q;
        const float v = acc[0][m][q] + bv;
        outS[(size_t)(row0 + rr) * 128 + cc] = v;
        *(short*)(sm + LDS_S + rr * 256 + ((cc * 2) ^ ((rr & 7) << 4))) = f2bf(v);
      }
    #pragma unroll
    for (int i = 0; i < 8; ++i)
      *(f32x4*)(sm + LDS_H0 + tid * 128 + i * 16) = (f32x4){0.f, 0.f, 0.f, 0.f};
  }
  __syncthreads();

  // ---- bias registers (lane-local columns)
  f32x4 b0v[2], b1v[2], bo1v, bo2v;
  #pragma unroll
  for (int js = 0; js < 2; ++js) {
    f32x4 t0, t1;
    #pragma unroll
    for (int g = 0; g < 4; ++g) {
      const int c = g * 256 + wid * 32 + js * 16 + l15;
      t0[g] = b_ih0[c] + b_hh0[c];
      t1[g] = b_ih1[c] + b_hh1[c];
    }
    b0v[js] = t0; b1v[js] = t1;
  }
  {
    f32x4 t = (f32x4){0.f, 0.f, 0.f, 0.f};
    #pragma unroll
    for (int nt = 0; nt < 2; ++nt) t[nt] = b_om1[wid * 32 + nt * 16 + l15];
    bo1v = t;
    #pragma unroll
    for (int nt = 0; nt < 4; ++nt) t[nt] = b_om2[wid * 64 + nt * 16 + l15];
    bo2v = t;
  }

  float c0a[16], c0b[16], c1a[16], c1b[16];
  #pragma unroll
  for (int i = 0; i < 16; ++i) { c0a[i] = 0.f; c0b[i] = 0.f; c1a[i] = 0.f; c1b[i] = 0.f; }

  for (int step = 0; step < nsteps; ++step) {
    unsigned hp[16];
    // ================ phase A: LSTM layer 0, A = [s | h0], K=384 ================
    {
      f32x4 acc[4][4]; zacc(acc);
      mm_tiles<12, 4, 4>(sm, LDS_S, 256, 256, LDS_H0, 512, wsb + OFF_W0, wid * 2 + 0, 16, acc, lane);
      lstm_ew(acc, b0v[0], c0a, hp, 0);
    }
    {
      f32x4 acc[4][4]; zacc(acc);
      mm_tiles<12, 4, 4>(sm, LDS_S, 256, 256, LDS_H0, 512, wsb + OFF_W0, wid * 2 + 1, 16, acc, lane);
      lstm_ew(acc, b0v[1], c0b, hp, 8);
    }
    __syncthreads();               // all reads of old h0 done
    #pragma unroll
    for (int js = 0; js < 2; ++js)
      #pragma unroll
      for (int m = 0; m < 4; ++m)
        #pragma unroll
        for (int q = 0; q < 4; ++q) {
          const int rr = m * 16 + l4 * 4 + q;
          const int cc = wid * 32 + js * 16 + l15;
          const unsigned v = hp[js * 8 + m * 2 + (q >> 1)] >> ((q & 1) * 16);
          *(short*)(sm + LDS_H0 + rr * 512 + ((cc * 2) ^ ((rr & 7) << 4))) = (short)v;
        }
    __syncthreads();
    // ================ phase B: LSTM layer 1, A = [h0 | h1], K=512 ================
    {
      f32x4 acc[4][4]; zacc(acc);
      mm_tiles<16, 4, 4>(sm, LDS_H0, 512, 512, LDS_H1, 512, wsb + OFF_W1, wid * 2 + 0, 16, acc, lane);
      lstm_ew(acc, b1v[0], c1a, hp, 0);
    }
    {
      f32x4 acc[4][4]; zacc(acc);
      mm_tiles<16, 4, 4>(sm, LDS_H0, 512, 512, LDS_H1, 512, wsb + OFF_W1, wid * 2 + 1, 16, acc, lane);
      lstm_ew(acc, b1v[1], c1b, hp, 8);
    }
    __syncthreads();               // all reads of old h1 done
    #pragma unroll
    for (int js = 0; js < 2; ++js)
      #pragma unroll
      for (int m = 0; m < 4; ++m)
        #pragma unroll
        for (int q = 0; q < 4; ++q) {
          const int rr = m * 16 + l4 * 4 + q;
          const int cc = wid * 32 + js * 16 + l15;
          const unsigned v = hp[js * 8 + m * 2 + (q >> 1)] >> ((q & 1) * 16);
          *(short*)(sm + LDS_H1 + rr * 512 + ((cc * 2) ^ ((rr & 7) << 4))) = (short)v;
        }
    __syncthreads();
    // ================ phase C: u = relu([h1|s] @ Wom1^T + b_om1) -> tS ================
    {
      f32x4 acc[2][4]; zacc(acc);
      mm_tiles<12, 2, 4>(sm, LDS_H1, 512, 512, LDS_S, 256, wsb + OFF_OM1, wid * 2, 1, acc, lane);
      #pragma unroll
      for (int nt = 0; nt < 2; ++nt)
        #pragma unroll
        for (int m = 0; m < 4; ++m)
          #pragma unroll
          for (int q = 0; q < 4; ++q) {
            const int rr = m * 16 + l4 * 4 + q;
            const int cc = wid * 32 + nt * 16 + l15;
            const float u = fmaxf(acc[nt][m][q] + bo1v[nt], 0.0f);
            *(short*)(sm + LDS_T + rr * 512 + ((cc * 2) ^ ((rr & 7) << 4))) = f2bf(u);
          }
    }
    __syncthreads();
    // ================ phase D: nxt = cur + 0.1*tanh(t @ Wom2^T + b_om2) ================
    {
      f32x4 acc[4][4]; zacc(acc);
      mm_tiles<8, 4, 4>(sm, LDS_T, 512, 512, LDS_T, 512, wsb + OFF_OM2, wid * 4, 1, acc, lane);
      #pragma unroll
      for (int nt = 0; nt < 4; ++nt)
        #pragma unroll
        for (int m = 0; m < 4; ++m)
          #pragma unroll
          for (int q = 0; q < 4; ++q) {
            const int rr = m * 16 + l4 * 4 + q;
            const int rg = row0 + rr;
            const int cc = wid * 64 + nt * 16 + l15;
            const float curv = (step == 0) ? base[(size_t)rg * 512 + cc]
                                           : outStates[((size_t)rg * nsteps + (step - 1)) * 512 + cc];
            const float nx = curv + 0.1f * tanh_(acc[nt][m][q] + bo2v[nt]);
            outStates[((size_t)rg * nsteps + step) * 512 + cc] = nx;
            if (step == nsteps - 1) outFinal[(size_t)rg * 512 + cc] = nx;
          }
    }
    // no barrier needed: next phase-A barrier orders tS reuse
  }
}

// ---------------- probability head: rows of states -> sigmoid(MLP) ----------------
#define PE_AS 0        // 32 x 512 bf16, stride 1024, swizzled
#define PE_P1 32768    // 32 x 128 bf16, stride 256, swizzled
#define PE_W2 40960    // 128 f32
#define PE_LDS 41472

__global__ __launch_bounds__(512, 4) void atg_pe(
    const float* __restrict__ states, float* __restrict__ probs,
    const float* __restrict__ b_pe1, const float* __restrict__ w_pe2,
    const float* __restrict__ b_pe2, const short* __restrict__ wpe1f, int totrows)
{
  __shared__ __align__(16) char sm[PE_LDS];
  const int tid = threadIdx.x;
  const int lane = tid & 63, wid = tid >> 6;
  const int l15 = lane & 15, l4 = lane >> 4;
  const int row0 = blockIdx.x * 32;

  {
    const int r = tid >> 4, ci = tid & 15;
    const float* src = states + (size_t)(row0 + r) * 512;
    #pragma unroll
    for (int i = 0; i < 8; ++i) {
      const int c = ci * 4 + i * 64;
      const float4 v = *(const float4*)(src + c);
      short4 h; h.x = f2bf(v.x); h.y = f2bf(v.y); h.z = f2bf(v.z); h.w = f2bf(v.w);
      *(short4*)(sm + PE_AS + r * 1024 + ((c * 2) ^ ((r & 7) << 4))) = h;
    }
  }
  if (tid < 128) *(float*)(sm + PE_W2 + tid * 4) = w_pe2[tid];
  __syncthreads();

  {
    f32x4 acc[1][2]; zacc(acc);
    mm_tiles<16, 1, 2>(sm, PE_AS, 1024, 1024, PE_AS, 1024, wpe1f, wid, 1, acc, lane);
    const int cc = wid * 16 + l15;
    const float bv = b_pe1[cc];
    #pragma unroll
    for (int m = 0; m < 2; ++m)
      #pragma unroll
      for (int q = 0; q < 4; ++q) {
        const int rr = m * 16 + l4 * 4 + q;
        const float u = fmaxf(acc[0][m][q] + bv, 0.0f);
        *(short*)(sm + PE_P1 + rr * 256 + ((cc * 2) ^ ((rr & 7) << 4))) = f2bf(u);
      }
  }
  __syncthreads();

  {
    const int r = tid >> 4, ci = tid & 15;
    const int kb = ci * 16;
    const bf16x8 pv = *(const bf16x8*)(sm + PE_P1 + r * 256 + (kb ^ ((r & 7) << 4)));
    float s = 0.0f;
    #pragma unroll
    for (int j = 0; j < 8; ++j)
      s += bf2f(pv[j]) * *(const float*)(sm + PE_W2 + (ci * 8 + j) * 4);
    #pragma unroll
    for (int d = 8; d >= 1; d >>= 1)
      s += __shfl_down(s, d, 16);
    if (ci == 0 && (row0 + r) < totrows)
      probs[row0 + r] = 1.0f / (1.0f + __expf(-(s + b_pe2[0])));
  }
}

extern "C" void kernel_launch(void* const* d_in, const int* in_sizes, int n_in,
                              void* d_out, int out_size, void* d_ws, size_t ws_size,
                              hipStream_t stream)
{
  const float* base  = (const float*)d_in[0];
  const float* cf    = (const float*)d_in[1];
  const float* w_se1 = (const float*)d_in[2];
  const float* b_se1 = (const float*)d_in[3];
  const float* w_se2 = (const float*)d_in[4];
  const float* b_se2 = (const float*)d_in[5];
  const float* w_ih0 = (const float*)d_in[6];
  const float* w_hh0 = (const float*)d_in[7];
  const float* b_ih0 = (const float*)d_in[8];
  const float* b_hh0 = (const float*)d_in[9];
  const float* w_ih1 = (const float*)d_in[10];
  const float* w_hh1 = (const float*)d_in[11];
  const float* b_ih1 = (const float*)d_in[12];
  const float* b_hh1 = (const float*)d_in[13];
  const float* w_om1 = (const float*)d_in[14];
  const float* b_om1 = (const float*)d_in[15];
  const float* w_om2 = (const float*)d_in[16];
  const float* b_om2 = (const float*)d_in[17];
  const float* w_pe1 = (const float*)d_in[18];
  const float* b_pe1 = (const float*)d_in[19];
  const float* w_pe2 = (const float*)d_in[20];
  const float* b_pe2 = (const float*)d_in[21];

  const int B = in_sizes[0] / 512;                               // 16384
  const long nsteps = ((long)out_size - (long)B * 640) / ((long)B * 513);  // 10
  short* wsb = (short*)d_ws;
  float* out = (float*)d_out;

  auto prep = [&](const float* A, const float* Bp, long off, int N, int K, int ks) {
    const int total = N * K;
    prep_frag<<<dim3((total + 255) / 256), dim3(256), 0, stream>>>(A, Bp, wsb + off, N, K, ks);
  };
  prep(w_se1, w_se1, OFF_SE1, 256, 512, 512);
  prep(w_se2, w_se2, OFF_SE2, 128, 256, 256);
  prep(w_ih0, w_hh0, OFF_W0, 1024, 384, 128);
  prep(w_ih1, w_hh1, OFF_W1, 1024, 512, 256);
  prep(w_om1, w_om1, OFF_OM1, 256, 384, 384);
  prep(w_om2, w_om2, OFF_OM2, 512, 256, 256);
  prep(w_pe1, w_pe1, OFF_PE1, 128, 512, 512);

  float* outS = out + (size_t)B * nsteps * 513;   // after states + probs
  float* outF = outS + (size_t)B * 128;
  atg_main<<<dim3(B / 64), dim3(512), 0, stream>>>(base, cf, b_se1, b_se2, b_ih0, b_hh0,
      b_ih1, b_hh1, b_om1, b_om2, wsb, out, outS, outF, (int)nsteps);

  const long totrows = (long)B * nsteps;
  float* probs = out + (size_t)B * nsteps * 512;
  atg_pe<<<dim3((int)(totrows / 32)), dim3(512), 0, stream>>>(out, probs, b_pe1, w_pe2, b_pe2,
      wsb + OFF_PE1, (int)totrows);
}